// Round 1
// baseline (106.263 us; speedup 1.0000x reference)
//
#include <hip/hip_runtime.h>
#include <math.h>

#define NSAMP 1024
#define DIM   64
#define ROWS  4     // n-rows per block
#define JT    64    // j-tile staged in LDS
#define NLAYER 3

__global__ __launch_bounds__(256) void ib_partial(
    const float* __restrict__ fea0, const float* __restrict__ fea1,
    const float* __restrict__ fea2, const float* __restrict__ fea3,
    const float* __restrict__ W_mu, const float* __restrict__ b_mu,
    const float* __restrict__ W_var, const float* __restrict__ b_var,
    float* __restrict__ partials)
{
    const int layer = blockIdx.y;
    const float* feas[4] = {fea0, fea1, fea2, fea3};
    const float* __restrict__ fr_p = feas[layer];      // reference features
    const float* __restrict__ fs_p = feas[layer + 1];  // student features

    const int tid = threadIdx.x;
    const int d   = tid & 63;
    const int nl  = tid >> 6;
    const int n   = blockIdx.x * ROWS + nl;

    __shared__ float fs[ROWS][DIM];
    __shared__ float fr[JT][DIM];   // lanes read stride-1 over d -> conflict-free
    __shared__ float wsum[4];

    // stage the 4 student rows
    fs[nl][d] = fs_p[n * DIM + d];
    __syncthreads();

    // mu[n,d] = sum_k fs[n,k] * W_mu[layer][d,k] + b_mu ; same for var head
    const float* __restrict__ wm = W_mu + (layer * DIM + d) * DIM;
    const float* __restrict__ wv = W_var + (layer * DIM + d) * DIM;
    float am = 0.f, av = 0.f;
#pragma unroll
    for (int k = 0; k < DIM; ++k) {
        const float f = fs[nl][k];          // LDS broadcast within wave
        am = fmaf(f, wm[k], am);
        av = fmaf(f, wv[k], av);
    }
    const float mu = am + b_mu[layer * DIM + d];
    const float x  = av + b_var[layer * DIM + d];
    // jax.nn.softplus(x) = max(x,0) + log1p(exp(-|x|))
    const float sp  = fmaxf(x, 0.f) + log1pf(expf(-fabsf(x)));
    const float var = sp * 0.1f + 1e-6f;

    // pairwise term: P[n,d] = sum_j |f_r[j,d] - mu[n,d]|
    float psum = 0.f;
    for (int j0 = 0; j0 < NSAMP; j0 += JT) {
        __syncthreads();  // previous tile fully consumed
#pragma unroll
        for (int t = 0; t < (JT * DIM) / 256; ++t) {
            const int l = tid + t * 256;
            ((float*)fr)[l] = fr_p[j0 * DIM + l];   // coalesced
        }
        __syncthreads();
#pragma unroll
        for (int j = 0; j < JT; ++j) {
            psum += fabsf(fr[j][d] - mu);           // sub + abs-add
        }
    }

    const float frnd = fr_p[n * DIM + d];
    // positive.sum - negative.sum contribution of this (n,d):
    float t = (psum * (1.0f / NSAMP) - fabsf(mu - frnd)) / var;

    // deterministic block reduction: wave shuffle then 4-way LDS
#pragma unroll
    for (int off = 32; off > 0; off >>= 1)
        t += __shfl_down(t, off, 64);
    if ((tid & 63) == 0) wsum[tid >> 6] = t;
    __syncthreads();
    if (tid == 0)
        partials[blockIdx.y * gridDim.x + blockIdx.x] =
            wsum[0] + wsum[1] + wsum[2] + wsum[3];
}

__global__ __launch_bounds__(256) void ib_final(
    const float* __restrict__ partials, int np, float* __restrict__ out)
{
    const int tid = threadIdx.x;
    float s = 0.f;
    for (int i = tid; i < np; i += 256) s += partials[i];
#pragma unroll
    for (int off = 32; off > 0; off >>= 1)
        s += __shfl_down(s, off, 64);
    __shared__ float wsum[4];
    if ((tid & 63) == 0) wsum[tid >> 6] = s;
    __syncthreads();
    if (tid == 0)
        out[0] = (wsum[0] + wsum[1] + wsum[2] + wsum[3]) * (1.0f / NSAMP);
}

extern "C" void kernel_launch(void* const* d_in, const int* in_sizes, int n_in,
                              void* d_out, int out_size, void* d_ws, size_t ws_size,
                              hipStream_t stream) {
    const float* fea0  = (const float*)d_in[0];
    const float* fea1  = (const float*)d_in[1];
    const float* fea2  = (const float*)d_in[2];
    const float* fea3  = (const float*)d_in[3];
    const float* W_mu  = (const float*)d_in[4];
    const float* b_mu  = (const float*)d_in[5];
    const float* W_var = (const float*)d_in[6];
    const float* b_var = (const float*)d_in[7];
    float* out = (float*)d_out;
    float* partials = (float*)d_ws;

    const int nblk = NSAMP / ROWS;          // 256 blocks per layer
    dim3 grid(nblk, NLAYER);
    ib_partial<<<grid, 256, 0, stream>>>(fea0, fea1, fea2, fea3,
                                         W_mu, b_mu, W_var, b_var, partials);
    ib_final<<<1, 256, 0, stream>>>(partials, nblk * NLAYER, out);
}

// Round 2
// 34.452 us; speedup vs baseline: 3.0844x; 3.0844x over previous
//
#include <hip/hip_runtime.h>
#include <math.h>

#define NSAMP 1024
#define DIM   64
#define NLAYER 3

// pairwise kernel tiling
#define JC 64                    // j rows per chunk (staged in LDS)
#define JS (NSAMP / JC)          // 16 j-chunks
#define NT 64                    // n rows per block
#define RT 4                     // n rows per thread
#define NTILES (NSAMP / NT)      // 16 n-tiles

// workspace layout (in floats)
#define MU_OFF   0
#define INV_OFF  (NLAYER * NSAMP * DIM)        // 196608
#define PART_OFF (2 * NLAYER * NSAMP * DIM)    // 393216
#define NPART    (NTILES * JS * NLAYER)        // 768
#define WS_REQ   ((size_t)(PART_OFF + NPART) * sizeof(float))

// ---------------------------------------------------------------------------
// head precompute: mu[l,n,d], inv_var[l,n,d]  -> d_ws
// grid (256, 3), block 256: 4 n-rows per block
__global__ __launch_bounds__(256) void ib_head(
    const float* __restrict__ f1, const float* __restrict__ f2,
    const float* __restrict__ f3,
    const float* __restrict__ W_mu, const float* __restrict__ b_mu,
    const float* __restrict__ W_var, const float* __restrict__ b_var,
    float* __restrict__ ws)
{
    const int layer = blockIdx.y;
    const float* __restrict__ fs_p = (layer == 0) ? f1 : (layer == 1) ? f2 : f3;

    const int tid = threadIdx.x;
    const int d   = tid & 63;
    const int nl  = tid >> 6;
    const int n   = blockIdx.x * 4 + nl;

    __shared__ float fs[4][DIM];
    fs[nl][d] = fs_p[n * DIM + d];
    __syncthreads();

    const float4* __restrict__ wm = (const float4*)(W_mu + (layer * DIM + d) * DIM);
    const float4* __restrict__ wv = (const float4*)(W_var + (layer * DIM + d) * DIM);
    float am = 0.f, av = 0.f;
#pragma unroll
    for (int k = 0; k < DIM / 4; ++k) {
        const float4 m4 = wm[k];
        const float4 v4 = wv[k];
        const float f0 = fs[nl][k * 4 + 0];
        const float f1v = fs[nl][k * 4 + 1];
        const float f2v = fs[nl][k * 4 + 2];
        const float f3v = fs[nl][k * 4 + 3];
        am = fmaf(f0, m4.x, am); am = fmaf(f1v, m4.y, am);
        am = fmaf(f2v, m4.z, am); am = fmaf(f3v, m4.w, am);
        av = fmaf(f0, v4.x, av); av = fmaf(f1v, v4.y, av);
        av = fmaf(f2v, v4.z, av); av = fmaf(f3v, v4.w, av);
    }
    const float mu = am + b_mu[layer * DIM + d];
    const float x  = av + b_var[layer * DIM + d];
    const float sp  = fmaxf(x, 0.f) + log1pf(expf(-fabsf(x)));
    const float var = sp * 0.1f + 1e-6f;

    const int o = (layer * NSAMP + n) * DIM + d;
    ws[MU_OFF + o]  = mu;
    ws[INV_OFF + o] = 1.0f / var;
}

// ---------------------------------------------------------------------------
// pairwise kernel: each block = (n-tile of 64 rows) x (j-chunk of 64) x layer
// thread: q = tid&15 owns d = 4q..4q+3 ; rg = tid>>4 owns rows n0+rg*4 .. +3
__global__ __launch_bounds__(256) void ib_pair(
    const float* __restrict__ fea0, const float* __restrict__ fea1,
    const float* __restrict__ fea2,
    const float* __restrict__ ws, float* __restrict__ partials)
{
    const int layer = blockIdx.z;
    const int ntile = blockIdx.x;
    const int jc    = blockIdx.y;
    const float* __restrict__ fr_p =
        (layer == 0) ? fea0 : (layer == 1) ? fea1 : fea2;

    const int tid = threadIdx.x;
    const int q   = tid & 15;
    const int rg  = tid >> 4;
    const int n0  = ntile * NT + rg * RT;
    const int d0  = q * 4;

    __shared__ float4 fr[JC][DIM / 4];   // 16 KB
    __shared__ float  wsum[4];

    // stage j-chunk (64 rows x 64 floats), coalesced float4
    const float4* __restrict__ src = (const float4*)(fr_p + jc * JC * DIM);
#pragma unroll
    for (int t = 0; t < 4; ++t)
        ((float4*)fr)[tid + t * 256] = src[tid + t * 256];

    // load mu for my 4 rows (16 float4 per row stride)
    const float4* __restrict__ mup =
        (const float4*)(ws + MU_OFF + (layer * NSAMP + n0) * DIM + d0);
    float4 mu[RT];
#pragma unroll
    for (int r = 0; r < RT; ++r) mu[r] = mup[r * (DIM / 4)];

    float4 ps[RT];
#pragma unroll
    for (int r = 0; r < RT; ++r) ps[r] = make_float4(0.f, 0.f, 0.f, 0.f);

    __syncthreads();
#pragma unroll 8
    for (int j = 0; j < JC; ++j) {
        const float4 f = fr[j][q];
#pragma unroll
        for (int r = 0; r < RT; ++r) {
            ps[r].x += fabsf(f.x - mu[r].x);
            ps[r].y += fabsf(f.y - mu[r].y);
            ps[r].z += fabsf(f.z - mu[r].z);
            ps[r].w += fabsf(f.w - mu[r].w);
        }
    }

    // epilogue: multiply by inv_var; jc==0 blocks also add the positive term
    const float4* __restrict__ ivp =
        (const float4*)(ws + INV_OFF + (layer * NSAMP + n0) * DIM + d0);
    const float inv_n = 1.0f / (float)NSAMP;
    float s = 0.f;
    if (jc == 0) {
        const float4* __restrict__ fsp = (const float4*)(fr_p + n0 * DIM + d0);
#pragma unroll
        for (int r = 0; r < RT; ++r) {
            const float4 iv = ivp[r * (DIM / 4)];
            const float4 a  = fsp[r * (DIM / 4)];
            s += (ps[r].x * inv_n - fabsf(mu[r].x - a.x)) * iv.x;
            s += (ps[r].y * inv_n - fabsf(mu[r].y - a.y)) * iv.y;
            s += (ps[r].z * inv_n - fabsf(mu[r].z - a.z)) * iv.z;
            s += (ps[r].w * inv_n - fabsf(mu[r].w - a.w)) * iv.w;
        }
    } else {
#pragma unroll
        for (int r = 0; r < RT; ++r) {
            const float4 iv = ivp[r * (DIM / 4)];
            s += ps[r].x * inv_n * iv.x;
            s += ps[r].y * inv_n * iv.y;
            s += ps[r].z * inv_n * iv.z;
            s += ps[r].w * inv_n * iv.w;
        }
    }

    // deterministic block reduction
#pragma unroll
    for (int off = 32; off > 0; off >>= 1)
        s += __shfl_down(s, off, 64);
    if ((tid & 63) == 0) wsum[tid >> 6] = s;
    __syncthreads();
    if (tid == 0)
        partials[(blockIdx.z * JS + blockIdx.y) * NTILES + blockIdx.x] =
            wsum[0] + wsum[1] + wsum[2] + wsum[3];
}

// ---------------------------------------------------------------------------
__global__ __launch_bounds__(256) void ib_final(
    const float* __restrict__ partials, int np, float scale,
    float* __restrict__ out)
{
    const int tid = threadIdx.x;
    float s = 0.f;
    for (int i = tid; i < np; i += 256) s += partials[i];
#pragma unroll
    for (int off = 32; off > 0; off >>= 1)
        s += __shfl_down(s, off, 64);
    __shared__ float wsum[4];
    if ((tid & 63) == 0) wsum[tid >> 6] = s;
    __syncthreads();
    if (tid == 0) out[0] = (wsum[0] + wsum[1] + wsum[2] + wsum[3]) * scale;
}

// ---------------------------------------------------------------------------
// fallback (round-1 fused kernel) if ws is too small for the precompute path
__global__ __launch_bounds__(256) void ib_fused(
    const float* __restrict__ fea0, const float* __restrict__ fea1,
    const float* __restrict__ fea2, const float* __restrict__ fea3,
    const float* __restrict__ W_mu, const float* __restrict__ b_mu,
    const float* __restrict__ W_var, const float* __restrict__ b_var,
    float* __restrict__ partials)
{
    const int layer = blockIdx.y;
    const float* feas[4] = {fea0, fea1, fea2, fea3};
    const float* __restrict__ fr_p = feas[layer];
    const float* __restrict__ fs_p = feas[layer + 1];

    const int tid = threadIdx.x;
    const int d   = tid & 63;
    const int nl  = tid >> 6;
    const int n   = blockIdx.x * 4 + nl;

    __shared__ float fs[4][DIM];
    __shared__ float fr[JC][DIM];
    __shared__ float wsum[4];

    fs[nl][d] = fs_p[n * DIM + d];
    __syncthreads();

    const float* __restrict__ wm = W_mu + (layer * DIM + d) * DIM;
    const float* __restrict__ wv = W_var + (layer * DIM + d) * DIM;
    float am = 0.f, av = 0.f;
#pragma unroll
    for (int k = 0; k < DIM; ++k) {
        const float f = fs[nl][k];
        am = fmaf(f, wm[k], am);
        av = fmaf(f, wv[k], av);
    }
    const float mu = am + b_mu[layer * DIM + d];
    const float x  = av + b_var[layer * DIM + d];
    const float sp  = fmaxf(x, 0.f) + log1pf(expf(-fabsf(x)));
    const float var = sp * 0.1f + 1e-6f;

    float psum = 0.f;
    for (int j0 = 0; j0 < NSAMP; j0 += JC) {
        __syncthreads();
#pragma unroll
        for (int t = 0; t < (JC * DIM) / 256; ++t) {
            const int l = tid + t * 256;
            ((float*)fr)[l] = fr_p[j0 * DIM + l];
        }
        __syncthreads();
#pragma unroll
        for (int j = 0; j < JC; ++j)
            psum += fabsf(fr[j][d] - mu);
    }

    const float frnd = fr_p[n * DIM + d];
    float t = (psum * (1.0f / NSAMP) - fabsf(mu - frnd)) / var;

#pragma unroll
    for (int off = 32; off > 0; off >>= 1)
        t += __shfl_down(t, off, 64);
    if ((tid & 63) == 0) wsum[tid >> 6] = t;
    __syncthreads();
    if (tid == 0)
        partials[blockIdx.y * gridDim.x + blockIdx.x] =
            wsum[0] + wsum[1] + wsum[2] + wsum[3];
}

// ---------------------------------------------------------------------------
extern "C" void kernel_launch(void* const* d_in, const int* in_sizes, int n_in,
                              void* d_out, int out_size, void* d_ws, size_t ws_size,
                              hipStream_t stream) {
    const float* fea0  = (const float*)d_in[0];
    const float* fea1  = (const float*)d_in[1];
    const float* fea2  = (const float*)d_in[2];
    const float* fea3  = (const float*)d_in[3];
    const float* W_mu  = (const float*)d_in[4];
    const float* b_mu  = (const float*)d_in[5];
    const float* W_var = (const float*)d_in[6];
    const float* b_var = (const float*)d_in[7];
    float* out = (float*)d_out;
    float* ws  = (float*)d_ws;

    if (ws_size >= WS_REQ) {
        // head precompute: mu, 1/var
        ib_head<<<dim3(NSAMP / 4, NLAYER), 256, 0, stream>>>(
            fea1, fea2, fea3, W_mu, b_mu, W_var, b_var, ws);
        // pairwise
        ib_pair<<<dim3(NTILES, JS, NLAYER), 256, 0, stream>>>(
            fea0, fea1, fea2, ws, ws + PART_OFF);
        ib_final<<<1, 256, 0, stream>>>(ws + PART_OFF, NPART,
                                        1.0f / (float)NSAMP, out);
    } else {
        const int nblk = NSAMP / 4;
        ib_fused<<<dim3(nblk, NLAYER), 256, 0, stream>>>(
            fea0, fea1, fea2, fea3, W_mu, b_mu, W_var, b_var, ws);
        ib_final<<<1, 256, 0, stream>>>(ws, nblk * NLAYER,
                                        1.0f / (float)NSAMP, out);
    }
}